// Round 4
// baseline (721.082 us; speedup 1.0000x reference)
//
#include <hip/hip_runtime.h>

// Transformer block, MI355X gfx950.
// B=4 T=2048 D=1024 H=16 HD=64. Inputs fp32. OUTPUT = FLOAT32 (reference
// returns f32; round-1/3 failures were bf16 stores read back as f32 pairs).
// Regions: R0[0,16M) xn->attnb->xn2 | R1[16M,64M) qkvb->h | R2[64M,80M) vt->h
//          R3[80M,96M) y(bf16) | R4[96M,120M) weights.  Total 120 MiB.

#define TCTX 2048
#define DM   1024
#define HDIM 64

typedef __attribute__((ext_vector_type(8))) __bf16 bf16x8;
typedef __attribute__((ext_vector_type(4))) float  f32x4;
typedef __attribute__((ext_vector_type(8))) unsigned short u16x8;

__device__ __forceinline__ void gload16(void* lds, const void* g) {
  __builtin_amdgcn_global_load_lds(
      (const __attribute__((address_space(1))) unsigned int*)g,
      (__attribute__((address_space(3))) unsigned int*)lds, 16, 0, 0);
}

__device__ __forceinline__ unsigned short f2bf(float f) {
  union { float f; unsigned u; } a; a.f = f;
  return (unsigned short)((a.u + 0x7fffu + ((a.u >> 16) & 1u)) >> 16);
}
__device__ __forceinline__ float bf2f(unsigned short h) {
  union { unsigned u; float f; } a; a.u = ((unsigned)h) << 16;
  return a.f;
}

// ---------------- LayerNorm fp32 in -> bf16 out, 1 wave per row -----------
__global__ __launch_bounds__(256) void ln_k(
    const float* __restrict__ in, const float* __restrict__ w,
    const float* __restrict__ b, unsigned short* __restrict__ out)
{
  const int row  = blockIdx.x * 4 + (threadIdx.x >> 6);
  const int lane = threadIdx.x & 63;
  const float* rp = in + (size_t)row * DM;
  float4 v[4];
  float s = 0.f, s2 = 0.f;
#pragma unroll
  for (int c = 0; c < 4; ++c) {
    v[c] = *reinterpret_cast<const float4*>(rp + c * 256 + lane * 4);
    s  += v[c].x + v[c].y + v[c].z + v[c].w;
    s2 += v[c].x * v[c].x + v[c].y * v[c].y + v[c].z * v[c].z + v[c].w * v[c].w;
  }
#pragma unroll
  for (int m = 1; m < 64; m <<= 1) { s += __shfl_xor(s, m, 64); s2 += __shfl_xor(s2, m, 64); }
  const float mean = s * (1.f / DM);
  const float rstd = rsqrtf(s2 * (1.f / DM) - mean * mean + 1e-5f);
#pragma unroll
  for (int c = 0; c < 4; ++c) {
    const int col = c * 256 + lane * 4;
    float4 wv = *reinterpret_cast<const float4*>(w + col);
    float4 bv = *reinterpret_cast<const float4*>(b + col);
    ushort4 o;
    o.x = f2bf((v[c].x - mean) * rstd * wv.x + bv.x);
    o.y = f2bf((v[c].y - mean) * rstd * wv.y + bv.y);
    o.z = f2bf((v[c].z - mean) * rstd * wv.z + bv.z);
    o.w = f2bf((v[c].w - mean) * rstd * wv.w + bv.w);
    *reinterpret_cast<ushort4*>(out + (size_t)row * DM + col) = o;
  }
}

// ---------------- LayerNorm bf16 in -> bf16 out ---------------------------
__global__ __launch_bounds__(256) void ln_bf_k(
    const unsigned short* __restrict__ in, const float* __restrict__ w,
    const float* __restrict__ b, unsigned short* __restrict__ out)
{
  const int row  = blockIdx.x * 4 + (threadIdx.x >> 6);
  const int lane = threadIdx.x & 63;
  const unsigned short* rp = in + (size_t)row * DM;
  float f[16];
  float s = 0.f, s2 = 0.f;
#pragma unroll
  for (int c = 0; c < 2; ++c) {
    u16x8 v = *reinterpret_cast<const u16x8*>(rp + c * 512 + lane * 8);
#pragma unroll
    for (int j = 0; j < 8; ++j) {
      const float ff = bf2f(v[j]);
      f[c * 8 + j] = ff;
      s += ff; s2 += ff * ff;
    }
  }
#pragma unroll
  for (int m = 1; m < 64; m <<= 1) { s += __shfl_xor(s, m, 64); s2 += __shfl_xor(s2, m, 64); }
  const float mean = s * (1.f / DM);
  const float rstd = rsqrtf(s2 * (1.f / DM) - mean * mean + 1e-5f);
#pragma unroll
  for (int c = 0; c < 2; ++c) {
    const int col = c * 512 + lane * 8;
    u16x8 o;
#pragma unroll
    for (int j = 0; j < 8; j += 4) {
      float4 wv = *reinterpret_cast<const float4*>(w + col + j);
      float4 bv = *reinterpret_cast<const float4*>(b + col + j);
      o[j + 0] = f2bf((f[c * 8 + j + 0] - mean) * rstd * wv.x + bv.x);
      o[j + 1] = f2bf((f[c * 8 + j + 1] - mean) * rstd * wv.y + bv.y);
      o[j + 2] = f2bf((f[c * 8 + j + 2] - mean) * rstd * wv.z + bv.z);
      o[j + 3] = f2bf((f[c * 8 + j + 3] - mean) * rstd * wv.w + bv.w);
    }
    *reinterpret_cast<u16x8*>(out + (size_t)row * DM + col) = o;
  }
}

// ---------- fp32 [R,C] -> bf16 [C,R] transpose (weight prep) --------------
__global__ void tr_f32_bf16(const float* __restrict__ in, unsigned short* __restrict__ out,
                            int R, int C, long ibs, long obs)
{
  __shared__ float tile[32][33];
  in  += (size_t)blockIdx.z * ibs;
  out += (size_t)blockIdx.z * obs;
  const int c0 = blockIdx.x * 32, r0 = blockIdx.y * 32;
  for (int i = threadIdx.y; i < 32; i += 8)
    tile[i][threadIdx.x] = in[(size_t)(r0 + i) * C + c0 + threadIdx.x];
  __syncthreads();
  for (int i = threadIdx.y; i < 32; i += 8)
    out[(size_t)(c0 + i) * R + r0 + threadIdx.x] = f2bf(tile[threadIdx.x][i]);
}

// ---------- V^T: qkv V block -> vt[b*16+h][e(64)][t(2048)] ----------------
__global__ void tr_v(const unsigned short* __restrict__ qkv, unsigned short* __restrict__ vt)
{
  __shared__ unsigned short tile[32][33];
  const int z = blockIdx.z, b = z >> 4, h = z & 15;
  const unsigned short* in = qkv + ((size_t)b * TCTX) * 3072 + 2048 + h * HDIM;
  unsigned short* out = vt + (size_t)z * HDIM * TCTX;
  const int c0 = blockIdx.x * 32, r0 = blockIdx.y * 32;
  for (int i = threadIdx.y; i < 32; i += 8)
    tile[i][threadIdx.x] = in[(size_t)(r0 + i) * 3072 + c0 + threadIdx.x];
  __syncthreads();
  for (int i = threadIdx.y; i < 32; i += 8)
    out[(size_t)(c0 + i) * TCTX + r0 + threadIdx.x] = tile[threadIdx.x][i];
}

// ---------- m97-structure GEMM: A[M,K] * Bt[N,K]^T, 128x128 tile, BK=32 ---
// EPI: 0 = bf16 store; 2 = bf16 relu(acc + bias);
//      3 = bf16 (f32 resid + acc + bias);
//      4 = FLOAT32 store (bf16 resid + acc + bias)  <- final output
template<int EPI>
__global__ __launch_bounds__(256) void gemm_k(
    const unsigned short* __restrict__ A, const unsigned short* __restrict__ Bt,
    void* __restrict__ Cp, const float* __restrict__ bias,
    const void* __restrict__ resid, int M, int N, int K)
{
  __shared__ unsigned short sA[128 * 32];
  __shared__ unsigned short sB[128 * 32];
  const int tid = threadIdx.x;
  const int bm = blockIdx.x, bn = blockIdx.y;
  const int w = tid >> 6, lane = tid & 63, lr = lane & 15, lg = lane >> 4;
  const int wm = w >> 1, wn = w & 1;

  const unsigned short* ga  = A  + (size_t)(bm * 128 + (tid >> 2)) * K + (tid & 3) * 8;
  const unsigned short* ga2 = ga + (size_t)64 * K;
  const unsigned short* gb  = Bt + (size_t)(bn * 128 + (tid >> 2)) * K + (tid & 3) * 8;
  const unsigned short* gb2 = gb + (size_t)64 * K;

  const f32x4 z4 = {0.f, 0.f, 0.f, 0.f};
  f32x4 acc[4][4];
#pragma unroll
  for (int i = 0; i < 4; ++i)
#pragma unroll
    for (int j = 0; j < 4; ++j) acc[i][j] = z4;

  const unsigned short* sAa = sA + (wm * 64 + lr) * 32 + lg * 8;
  const unsigned short* sBb = sB + (wn * 64 + lr) * 32 + lg * 8;

  for (int k0 = 0; k0 < K; k0 += 32) {
    gload16(sA + (size_t)tid * 8, ga);
    gload16(sA + (size_t)(256 + tid) * 8, ga2);
    gload16(sB + (size_t)tid * 8, gb);
    gload16(sB + (size_t)(256 + tid) * 8, gb2);
    ga += 32; ga2 += 32; gb += 32; gb2 += 32;
    __syncthreads();
    bf16x8 af[4], bfr[4];
#pragma unroll
    for (int i = 0; i < 4; ++i) af[i]  = *reinterpret_cast<const bf16x8*>(sAa + i * 512);
#pragma unroll
    for (int j = 0; j < 4; ++j) bfr[j] = *reinterpret_cast<const bf16x8*>(sBb + j * 512);
#pragma unroll
    for (int i = 0; i < 4; ++i)
#pragma unroll
      for (int j = 0; j < 4; ++j)
        acc[i][j] = __builtin_amdgcn_mfma_f32_16x16x32_bf16(af[i], bfr[j], acc[i][j], 0, 0, 0);
    __syncthreads();
  }

  const int row0 = bm * 128 + wm * 64 + lg * 4;
  const int col0 = bn * 128 + wn * 64 + lr;
#pragma unroll
  for (int i = 0; i < 4; ++i) {
#pragma unroll
    for (int j = 0; j < 4; ++j) {
      const int c = col0 + j * 16;
#pragma unroll
      for (int r = 0; r < 4; ++r) {
        const int rr = row0 + i * 16 + r;
        const size_t idx = (size_t)rr * N + c;
        const float v = acc[i][j][r];
        if constexpr (EPI == 0) {
          ((unsigned short*)Cp)[idx] = f2bf(v);
        } else if constexpr (EPI == 2) {
          const float o = v + bias[c];
          ((unsigned short*)Cp)[idx] = f2bf(o > 0.f ? o : 0.f);
        } else if constexpr (EPI == 3) {
          ((unsigned short*)Cp)[idx] = f2bf(((const float*)resid)[idx] + v + bias[c]);
        } else {
          ((float*)Cp)[idx] = bf2f(((const unsigned short*)resid)[idx]) + v + bias[c];
        }
      }
    }
  }
}

// ---------- causal flash attention, 4 waves x 32 q-rows, 64-key tiles -----
__global__ __launch_bounds__(256) void attn_k(
    const unsigned short* __restrict__ qkv, const unsigned short* __restrict__ vt,
    unsigned short* __restrict__ out)
{
  __shared__ unsigned short sK[64 * 64];       // XOR-swizzled 16B chunks
  __shared__ unsigned short sV[64 * 64];       // vt tile, same swizzle
  __shared__ unsigned short sP[4][32 * 72];    // per-wave P, padded rows

  const int qb = (int)gridDim.x - 1 - (int)blockIdx.x;  // heavy blocks first
  const int z = blockIdx.y, b = z >> 4, h = z & 15;
  const int tid = threadIdx.x;
  const int wv_ = tid >> 6, lane = tid & 63, lr = lane & 15, lg = lane >> 4;
  const int q_lo = qb * 128 + wv_ * 32;

  bf16x8 qf[2][2];
#pragma unroll
  for (int mt = 0; mt < 2; ++mt)
#pragma unroll
    for (int kk = 0; kk < 2; ++kk)
      qf[mt][kk] = *reinterpret_cast<const bf16x8*>(
          qkv + ((size_t)(b * TCTX + q_lo + mt * 16 + lr)) * 3072 + h * HDIM + kk * 32 + lg * 8);

  const f32x4 z4 = {0.f, 0.f, 0.f, 0.f};
  f32x4 accO[2][4];
  float rm[2][4], rl[2][4];
#pragma unroll
  for (int mt = 0; mt < 2; ++mt) {
#pragma unroll
    for (int et = 0; et < 4; ++et) accO[mt][et] = z4;
#pragma unroll
    for (int r = 0; r < 4; ++r) { rm[mt][r] = -1e30f; rl[mt][r] = 0.f; }
  }

  const int srow = tid >> 3, sch = tid & 7;
  const int sc1 = sch ^ (srow & 7);
  unsigned short* sPw = sP[wv_];

  const int nkv = 2 * qb + 2;
  for (int t = 0; t < nkv; ++t) {
    const int kvb = t * 64;
    __syncthreads();
    gload16(sK + (size_t)tid * 8,
            qkv + ((size_t)(b * TCTX + kvb + srow)) * 3072 + 1024 + h * HDIM + sc1 * 8);
    gload16(sK + (size_t)(256 + tid) * 8,
            qkv + ((size_t)(b * TCTX + kvb + 32 + srow)) * 3072 + 1024 + h * HDIM + sc1 * 8);
    gload16(sV + (size_t)tid * 8,
            vt + ((size_t)(z * 64 + srow)) * TCTX + kvb + sc1 * 8);
    gload16(sV + (size_t)(256 + tid) * 8,
            vt + ((size_t)(z * 64 + 32 + srow)) * TCTX + kvb + sc1 * 8);
    __syncthreads();
    if (kvb > q_lo + 31) continue;

    f32x4 accS[2][4];
#pragma unroll
    for (int mt = 0; mt < 2; ++mt)
#pragma unroll
      for (int nt = 0; nt < 4; ++nt) accS[mt][nt] = z4;
#pragma unroll
    for (int nt = 0; nt < 4; ++nt) {
      const int krow = nt * 16 + lr;
#pragma unroll
      for (int kk = 0; kk < 2; ++kk) {
        const int boff = ((krow * 64 + kk * 32 + lg * 8) * 2) ^ ((krow & 7) << 4);
        bf16x8 kf = *reinterpret_cast<const bf16x8*>((const char*)sK + boff);
        accS[0][nt] = __builtin_amdgcn_mfma_f32_16x16x32_bf16(qf[0][kk], kf, accS[0][nt], 0, 0, 0);
        accS[1][nt] = __builtin_amdgcn_mfma_f32_16x16x32_bf16(qf[1][kk], kf, accS[1][nt], 0, 0, 0);
      }
    }
#pragma unroll
    for (int mt = 0; mt < 2; ++mt) {
#pragma unroll
      for (int r = 0; r < 4; ++r) {
        const int q = q_lo + mt * 16 + lg * 4 + r;
        float mx = -1e30f;
#pragma unroll
        for (int nt = 0; nt < 4; ++nt) {
          float sv = accS[mt][nt][r] * 0.125f;
          if (kvb + nt * 16 + lr > q) sv = -1e30f;
          accS[mt][nt][r] = sv;
          mx = fmaxf(mx, sv);
        }
#pragma unroll
        for (int m = 1; m < 16; m <<= 1) mx = fmaxf(mx, __shfl_xor(mx, m, 64));
        const float mo = rm[mt][r];
        const float mn = fmaxf(mo, mx);
        const float sf = __expf(mo - mn);
        float rs = 0.f;
#pragma unroll
        for (int nt = 0; nt < 4; ++nt) {
          const float p = __expf(accS[mt][nt][r] - mn);
          rs += p;
          sPw[(mt * 16 + lg * 4 + r) * 72 + nt * 16 + lr] = f2bf(p);
        }
#pragma unroll
        for (int m = 1; m < 16; m <<= 1) rs += __shfl_xor(rs, m, 64);
        rm[mt][r] = mn;
        rl[mt][r] = rl[mt][r] * sf + rs;
#pragma unroll
        for (int et = 0; et < 4; ++et) accO[mt][et][r] *= sf;
      }
    }
#pragma unroll
    for (int kk = 0; kk < 2; ++kk) {
      bf16x8 pa0 = *reinterpret_cast<const bf16x8*>(sPw + (0 * 16 + lr) * 72 + kk * 32 + lg * 8);
      bf16x8 pa1 = *reinterpret_cast<const bf16x8*>(sPw + (1 * 16 + lr) * 72 + kk * 32 + lg * 8);
#pragma unroll
      for (int et = 0; et < 4; ++et) {
        const int vrow = et * 16 + lr;
        const int boff = ((vrow * 64 + kk * 32 + lg * 8) * 2) ^ ((vrow & 7) << 4);
        bf16x8 vf = *reinterpret_cast<const bf16x8*>((const char*)sV + boff);
        accO[0][et] = __builtin_amdgcn_mfma_f32_16x16x32_bf16(pa0, vf, accO[0][et], 0, 0, 0);
        accO[1][et] = __builtin_amdgcn_mfma_f32_16x16x32_bf16(pa1, vf, accO[1][et], 0, 0, 0);
      }
    }
  }
#pragma unroll
  for (int mt = 0; mt < 2; ++mt)
#pragma unroll
    for (int r = 0; r < 4; ++r) {
      const int q = q_lo + mt * 16 + lg * 4 + r;
      const float inv = 1.f / rl[mt][r];
#pragma unroll
      for (int et = 0; et < 4; ++et)
        out[((size_t)(b * TCTX + q)) * DM + h * HDIM + et * 16 + lr] =
            f2bf(accO[mt][et][r] * inv);
    }
}

extern "C" void kernel_launch(void* const* d_in, const int* in_sizes, int n_in,
                              void* d_out, int out_size, void* d_ws, size_t ws_size,
                              hipStream_t stream)
{
  const float* x     = (const float*)d_in[0];
  const float* ln1w  = (const float*)d_in[1];
  const float* ln1b  = (const float*)d_in[2];
  const float* wq    = (const float*)d_in[3];
  const float* wk    = (const float*)d_in[4];
  const float* wvp   = (const float*)d_in[5];
  const float* wproj = (const float*)d_in[6];
  const float* bproj = (const float*)d_in[7];
  const float* ln2w  = (const float*)d_in[8];
  const float* ln2b  = (const float*)d_in[9];
  const float* w1    = (const float*)d_in[10];
  const float* b1    = (const float*)d_in[11];
  const float* w2    = (const float*)d_in[12];
  const float* b2    = (const float*)d_in[13];

  char* ws = (char*)d_ws;
  // 120 MiB layout
  unsigned short* xn     = (unsigned short*)(ws + 0);             // 16 MiB R0
  unsigned short* qkvb   = (unsigned short*)(ws + 16777216);      // 48 MiB R1
  unsigned short* vtb    = (unsigned short*)(ws + 67108864);      // 16 MiB R2
  unsigned short* ybf    = (unsigned short*)(ws + 83886080);      // 16 MiB R3
  unsigned short* wqkvT  = (unsigned short*)(ws + 100663296);     // 6 MiB
  unsigned short* wprojT = (unsigned short*)(ws + 106954752);     // 2 MiB
  unsigned short* w1T    = (unsigned short*)(ws + 109051904);     // 8 MiB
  unsigned short* w2T    = (unsigned short*)(ws + 117440512);     // 8 MiB  (ends 120 MiB)
  unsigned short* attnb  = xn;     // R0 reuse
  unsigned short* xn2    = xn;     // R0 reuse (attnb dead after proj gemm)
  unsigned short* hb     = qkvb;   // R1+R2 reuse [8192,4096]

  dim3 tb(32, 8);
  tr_f32_bf16<<<dim3(2, 32, 16), tb, 0, stream>>>(wq,  wqkvT,               1024, 64, 65536, 65536);
  tr_f32_bf16<<<dim3(2, 32, 16), tb, 0, stream>>>(wk,  wqkvT + 1024 * 1024, 1024, 64, 65536, 65536);
  tr_f32_bf16<<<dim3(2, 32, 16), tb, 0, stream>>>(wvp, wqkvT + 2048 * 1024, 1024, 64, 65536, 65536);
  tr_f32_bf16<<<dim3(32, 32, 1),  tb, 0, stream>>>(wproj, wprojT, 1024, 1024, 0, 0);
  tr_f32_bf16<<<dim3(128, 32, 1), tb, 0, stream>>>(w1, w1T, 1024, 4096, 0, 0);
  tr_f32_bf16<<<dim3(32, 128, 1), tb, 0, stream>>>(w2, w2T, 4096, 1024, 0, 0);

  ln_k<<<2048, 256, 0, stream>>>(x, ln1w, ln1b, xn);
  gemm_k<0><<<dim3(64, 24), 256, 0, stream>>>(xn, wqkvT, qkvb, nullptr, nullptr, 8192, 3072, 1024);
  tr_v<<<dim3(2, 64, 64), tb, 0, stream>>>(qkvb, vtb);
  attn_k<<<dim3(16, 64), 256, 0, stream>>>(qkvb, vtb, attnb);
  gemm_k<3><<<dim3(64, 8), 256, 0, stream>>>(attnb, wprojT, ybf, bproj, x, 8192, 1024, 1024);
  ln_bf_k<<<2048, 256, 0, stream>>>(ybf, ln2w, ln2b, xn2);
  gemm_k<2><<<dim3(64, 32), 256, 0, stream>>>(xn2, w1T, hb, b1, nullptr, 8192, 4096, 1024);
  gemm_k<4><<<dim3(64, 8), 256, 0, stream>>>(hb, w2T, d_out, b2, ybf, 8192, 1024, 4096);
}

// Round 12
// 595.574 us; speedup vs baseline: 1.2107x; 1.2107x over previous
//
#include <hip/hip_runtime.h>

// Transformer block, MI355X gfx950.
// B=4 T=2048 D=1024 H=16 HD=64. Inputs fp32, output FLOAT32.
// R5 (7th resubmit; 6x GPUAcquisitionTimeout + 1x container-failed):
// attn_k gets (a) double-buffered K/V staging (stage t+1 before compute t,
// one barrier/tile), (b) balanced causal pairing (block = qb 15-bx then bx,
// 34 tiles each, grid 8x64), (c) s_setprio around MFMA clusters.
// Everything else byte-identical to the passing R4 kernel (721 us, absmax 0.031).

#define TCTX 2048
#define DM   1024
#define HDIM 64

typedef __attribute__((ext_vector_type(8))) __bf16 bf16x8;
typedef __attribute__((ext_vector_type(4))) float  f32x4;
typedef __attribute__((ext_vector_type(8))) unsigned short u16x8;

__device__ __forceinline__ void gload16(void* lds, const void* g) {
  __builtin_amdgcn_global_load_lds(
      (const __attribute__((address_space(1))) unsigned int*)g,
      (__attribute__((address_space(3))) unsigned int*)lds, 16, 0, 0);
}

__device__ __forceinline__ unsigned short f2bf(float f) {
  union { float f; unsigned u; } a; a.f = f;
  return (unsigned short)((a.u + 0x7fffu + ((a.u >> 16) & 1u)) >> 16);
}
__device__ __forceinline__ float bf2f(unsigned short h) {
  union { unsigned u; float f; } a; a.u = ((unsigned)h) << 16;
  return a.f;
}

// ---------------- LayerNorm fp32 in -> bf16 out, 1 wave per row -----------
__global__ __launch_bounds__(256) void ln_k(
    const float* __restrict__ in, const float* __restrict__ w,
    const float* __restrict__ b, unsigned short* __restrict__ out)
{
  const int row  = blockIdx.x * 4 + (threadIdx.x >> 6);
  const int lane = threadIdx.x & 63;
  const float* rp = in + (size_t)row * DM;
  float4 v[4];
  float s = 0.f, s2 = 0.f;
#pragma unroll
  for (int c = 0; c < 4; ++c) {
    v[c] = *reinterpret_cast<const float4*>(rp + c * 256 + lane * 4);
    s  += v[c].x + v[c].y + v[c].z + v[c].w;
    s2 += v[c].x * v[c].x + v[c].y * v[c].y + v[c].z * v[c].z + v[c].w * v[c].w;
  }
#pragma unroll
  for (int m = 1; m < 64; m <<= 1) { s += __shfl_xor(s, m, 64); s2 += __shfl_xor(s2, m, 64); }
  const float mean = s * (1.f / DM);
  const float rstd = rsqrtf(s2 * (1.f / DM) - mean * mean + 1e-5f);
#pragma unroll
  for (int c = 0; c < 4; ++c) {
    const int col = c * 256 + lane * 4;
    float4 wv = *reinterpret_cast<const float4*>(w + col);
    float4 bv = *reinterpret_cast<const float4*>(b + col);
    ushort4 o;
    o.x = f2bf((v[c].x - mean) * rstd * wv.x + bv.x);
    o.y = f2bf((v[c].y - mean) * rstd * wv.y + bv.y);
    o.z = f2bf((v[c].z - mean) * rstd * wv.z + bv.z);
    o.w = f2bf((v[c].w - mean) * rstd * wv.w + bv.w);
    *reinterpret_cast<ushort4*>(out + (size_t)row * DM + col) = o;
  }
}

// ---------------- LayerNorm bf16 in -> bf16 out ---------------------------
__global__ __launch_bounds__(256) void ln_bf_k(
    const unsigned short* __restrict__ in, const float* __restrict__ w,
    const float* __restrict__ b, unsigned short* __restrict__ out)
{
  const int row  = blockIdx.x * 4 + (threadIdx.x >> 6);
  const int lane = threadIdx.x & 63;
  const unsigned short* rp = in + (size_t)row * DM;
  float f[16];
  float s = 0.f, s2 = 0.f;
#pragma unroll
  for (int c = 0; c < 2; ++c) {
    u16x8 v = *reinterpret_cast<const u16x8*>(rp + c * 512 + lane * 8);
#pragma unroll
    for (int j = 0; j < 8; ++j) {
      const float ff = bf2f(v[j]);
      f[c * 8 + j] = ff;
      s += ff; s2 += ff * ff;
    }
  }
#pragma unroll
  for (int m = 1; m < 64; m <<= 1) { s += __shfl_xor(s, m, 64); s2 += __shfl_xor(s2, m, 64); }
  const float mean = s * (1.f / DM);
  const float rstd = rsqrtf(s2 * (1.f / DM) - mean * mean + 1e-5f);
#pragma unroll
  for (int c = 0; c < 2; ++c) {
    const int col = c * 512 + lane * 8;
    u16x8 o;
#pragma unroll
    for (int j = 0; j < 8; j += 4) {
      float4 wv = *reinterpret_cast<const float4*>(w + col + j);
      float4 bv = *reinterpret_cast<const float4*>(b + col + j);
      o[j + 0] = f2bf((f[c * 8 + j + 0] - mean) * rstd * wv.x + bv.x);
      o[j + 1] = f2bf((f[c * 8 + j + 1] - mean) * rstd * wv.y + bv.y);
      o[j + 2] = f2bf((f[c * 8 + j + 2] - mean) * rstd * wv.z + bv.z);
      o[j + 3] = f2bf((f[c * 8 + j + 3] - mean) * rstd * wv.w + bv.w);
    }
    *reinterpret_cast<u16x8*>(out + (size_t)row * DM + col) = o;
  }
}

// ---------- fp32 [R,C] -> bf16 [C,R] transpose (weight prep) --------------
__global__ void tr_f32_bf16(const float* __restrict__ in, unsigned short* __restrict__ out,
                            int R, int C, long ibs, long obs)
{
  __shared__ float tile[32][33];
  in  += (size_t)blockIdx.z * ibs;
  out += (size_t)blockIdx.z * obs;
  const int c0 = blockIdx.x * 32, r0 = blockIdx.y * 32;
  for (int i = threadIdx.y; i < 32; i += 8)
    tile[i][threadIdx.x] = in[(size_t)(r0 + i) * C + c0 + threadIdx.x];
  __syncthreads();
  for (int i = threadIdx.y; i < 32; i += 8)
    out[(size_t)(c0 + i) * R + r0 + threadIdx.x] = f2bf(tile[threadIdx.x][i]);
}

// ---------- V^T: qkv V block -> vt[b*16+h][e(64)][t(2048)] ----------------
__global__ void tr_v(const unsigned short* __restrict__ qkv, unsigned short* __restrict__ vt)
{
  __shared__ unsigned short tile[32][33];
  const int z = blockIdx.z, b = z >> 4, h = z & 15;
  const unsigned short* in = qkv + ((size_t)b * TCTX) * 3072 + 2048 + h * HDIM;
  unsigned short* out = vt + (size_t)z * HDIM * TCTX;
  const int c0 = blockIdx.x * 32, r0 = blockIdx.y * 32;
  for (int i = threadIdx.y; i < 32; i += 8)
    tile[i][threadIdx.x] = in[(size_t)(r0 + i) * 3072 + c0 + threadIdx.x];
  __syncthreads();
  for (int i = threadIdx.y; i < 32; i += 8)
    out[(size_t)(c0 + i) * TCTX + r0 + threadIdx.x] = tile[threadIdx.x][i];
}

// ---------- m97-structure GEMM: A[M,K] * Bt[N,K]^T, 128x128 tile, BK=32 ---
// EPI: 0 = bf16 store; 2 = bf16 relu(acc + bias);
//      3 = bf16 (f32 resid + acc + bias);
//      4 = FLOAT32 store (bf16 resid + acc + bias)  <- final output
template<int EPI>
__global__ __launch_bounds__(256) void gemm_k(
    const unsigned short* __restrict__ A, const unsigned short* __restrict__ Bt,
    void* __restrict__ Cp, const float* __restrict__ bias,
    const void* __restrict__ resid, int M, int N, int K)
{
  __shared__ unsigned short sA[128 * 32];
  __shared__ unsigned short sB[128 * 32];
  const int tid = threadIdx.x;
  const int bm = blockIdx.x, bn = blockIdx.y;
  const int w = tid >> 6, lane = tid & 63, lr = lane & 15, lg = lane >> 4;
  const int wm = w >> 1, wn = w & 1;

  const unsigned short* ga  = A  + (size_t)(bm * 128 + (tid >> 2)) * K + (tid & 3) * 8;
  const unsigned short* ga2 = ga + (size_t)64 * K;
  const unsigned short* gb  = Bt + (size_t)(bn * 128 + (tid >> 2)) * K + (tid & 3) * 8;
  const unsigned short* gb2 = gb + (size_t)64 * K;

  const f32x4 z4 = {0.f, 0.f, 0.f, 0.f};
  f32x4 acc[4][4];
#pragma unroll
  for (int i = 0; i < 4; ++i)
#pragma unroll
    for (int j = 0; j < 4; ++j) acc[i][j] = z4;

  const unsigned short* sAa = sA + (wm * 64 + lr) * 32 + lg * 8;
  const unsigned short* sBb = sB + (wn * 64 + lr) * 32 + lg * 8;

  for (int k0 = 0; k0 < K; k0 += 32) {
    gload16(sA + (size_t)tid * 8, ga);
    gload16(sA + (size_t)(256 + tid) * 8, ga2);
    gload16(sB + (size_t)tid * 8, gb);
    gload16(sB + (size_t)(256 + tid) * 8, gb2);
    ga += 32; ga2 += 32; gb += 32; gb2 += 32;
    __syncthreads();
    bf16x8 af[4], bfr[4];
#pragma unroll
    for (int i = 0; i < 4; ++i) af[i]  = *reinterpret_cast<const bf16x8*>(sAa + i * 512);
#pragma unroll
    for (int j = 0; j < 4; ++j) bfr[j] = *reinterpret_cast<const bf16x8*>(sBb + j * 512);
#pragma unroll
    for (int i = 0; i < 4; ++i)
#pragma unroll
      for (int j = 0; j < 4; ++j)
        acc[i][j] = __builtin_amdgcn_mfma_f32_16x16x32_bf16(af[i], bfr[j], acc[i][j], 0, 0, 0);
    __syncthreads();
  }

  const int row0 = bm * 128 + wm * 64 + lg * 4;
  const int col0 = bn * 128 + wn * 64 + lr;
#pragma unroll
  for (int i = 0; i < 4; ++i) {
#pragma unroll
    for (int j = 0; j < 4; ++j) {
      const int c = col0 + j * 16;
#pragma unroll
      for (int r = 0; r < 4; ++r) {
        const int rr = row0 + i * 16 + r;
        const size_t idx = (size_t)rr * N + c;
        const float v = acc[i][j][r];
        if constexpr (EPI == 0) {
          ((unsigned short*)Cp)[idx] = f2bf(v);
        } else if constexpr (EPI == 2) {
          const float o = v + bias[c];
          ((unsigned short*)Cp)[idx] = f2bf(o > 0.f ? o : 0.f);
        } else if constexpr (EPI == 3) {
          ((unsigned short*)Cp)[idx] = f2bf(((const float*)resid)[idx] + v + bias[c]);
        } else {
          ((float*)Cp)[idx] = bf2f(((const unsigned short*)resid)[idx]) + v + bias[c];
        }
      }
    }
  }
}

// ---------- causal flash attention -----------------------------------------
// 4 waves x 32 q-rows, 64-key tiles; double-buffered K/V staging (stage t+1
// before compute t, one barrier per tile); balanced pairing: block bx does
// qb=15-bx then qb=bx (34 tiles each). Grid (8, 64).
__global__ __launch_bounds__(256) void attn_k(
    const unsigned short* __restrict__ qkv, const unsigned short* __restrict__ vt,
    unsigned short* __restrict__ out)
{
  __shared__ unsigned short sK[2][64 * 64];    // XOR-swizzled 16B chunks, dbuf
  __shared__ unsigned short sV[2][64 * 64];
  __shared__ unsigned short sP[4][32 * 72];    // per-wave P, padded rows

  const int z = blockIdx.y, b = z >> 4, h = z & 15;
  const int tid = threadIdx.x;
  const int wv_ = tid >> 6, lane = tid & 63, lr = lane & 15, lg = lane >> 4;
  const int srow = tid >> 3, sch = tid & 7;
  const int sc1 = sch ^ (srow & 7);
  unsigned short* sPw = sP[wv_];

  const unsigned short* kbase =
      qkv + ((size_t)(b * TCTX + srow)) * 3072 + 1024 + h * HDIM + sc1 * 8;
  const unsigned short* vbase = vt + ((size_t)(z * 64 + srow)) * TCTX + sc1 * 8;

#define STAGE(buf, kvb) do {                                                  \
    gload16(sK[buf] + (size_t)tid * 8,         kbase + (size_t)(kvb) * 3072); \
    gload16(sK[buf] + (size_t)(256 + tid) * 8, kbase + (size_t)((kvb) + 32) * 3072); \
    gload16(sV[buf] + (size_t)tid * 8,         vbase + (kvb));                \
    gload16(sV[buf] + (size_t)(256 + tid) * 8, vbase + 32 * TCTX + (kvb));    \
  } while (0)

  const f32x4 z4 = {0.f, 0.f, 0.f, 0.f};

  for (int half = 0; half < 2; ++half) {
    const int qb = (half == 0) ? (15 - (int)blockIdx.x) : (int)blockIdx.x;
    const int q_lo = qb * 128 + wv_ * 32;

    bf16x8 qf[2][2];
#pragma unroll
    for (int mt = 0; mt < 2; ++mt)
#pragma unroll
      for (int kk = 0; kk < 2; ++kk)
        qf[mt][kk] = *reinterpret_cast<const bf16x8*>(
            qkv + ((size_t)(b * TCTX + q_lo + mt * 16 + lr)) * 3072 + h * HDIM + kk * 32 + lg * 8);

    f32x4 accO[2][4];
    float rm[2][4], rl[2][4];
#pragma unroll
    for (int mt = 0; mt < 2; ++mt) {
#pragma unroll
      for (int et = 0; et < 4; ++et) accO[mt][et] = z4;
#pragma unroll
      for (int r = 0; r < 4; ++r) { rm[mt][r] = -1e30f; rl[mt][r] = 0.f; }
    }

    const int nkv = 2 * qb + 2;
    int cur = 0;
    STAGE(0, 0);
    __syncthreads();

    for (int t = 0; t < nkv; ++t) {
      const int kvb = t * 64;
      if (t + 1 < nkv) STAGE(cur ^ 1, kvb + 64);   // prefetch next tile
      if (kvb <= q_lo + 31) {
        const unsigned short* sKc = sK[cur];
        const unsigned short* sVc = sV[cur];
        // S = Q K^T
        f32x4 accS[2][4];
#pragma unroll
        for (int mt = 0; mt < 2; ++mt)
#pragma unroll
          for (int nt = 0; nt < 4; ++nt) accS[mt][nt] = z4;
        __builtin_amdgcn_s_setprio(1);
#pragma unroll
        for (int nt = 0; nt < 4; ++nt) {
          const int krow = nt * 16 + lr;
#pragma unroll
          for (int kk = 0; kk < 2; ++kk) {
            const int boff = ((krow * 64 + kk * 32 + lg * 8) * 2) ^ ((krow & 7) << 4);
            bf16x8 kf = *reinterpret_cast<const bf16x8*>((const char*)sKc + boff);
            accS[0][nt] = __builtin_amdgcn_mfma_f32_16x16x32_bf16(qf[0][kk], kf, accS[0][nt], 0, 0, 0);
            accS[1][nt] = __builtin_amdgcn_mfma_f32_16x16x32_bf16(qf[1][kk], kf, accS[1][nt], 0, 0, 0);
          }
        }
        __builtin_amdgcn_s_setprio(0);
        // online softmax; P -> wave-private LDS
#pragma unroll
        for (int mt = 0; mt < 2; ++mt) {
#pragma unroll
          for (int r = 0; r < 4; ++r) {
            const int q = q_lo + mt * 16 + lg * 4 + r;
            float mx = -1e30f;
#pragma unroll
            for (int nt = 0; nt < 4; ++nt) {
              float sv = accS[mt][nt][r] * 0.125f;
              if (kvb + nt * 16 + lr > q) sv = -1e30f;
              accS[mt][nt][r] = sv;
              mx = fmaxf(mx, sv);
            }
#pragma unroll
            for (int m = 1; m < 16; m <<= 1) mx = fmaxf(mx, __shfl_xor(mx, m, 64));
            const float mo = rm[mt][r];
            const float mn = fmaxf(mo, mx);
            const float sf = __expf(mo - mn);
            float rs = 0.f;
#pragma unroll
            for (int nt = 0; nt < 4; ++nt) {
              const float p = __expf(accS[mt][nt][r] - mn);
              rs += p;
              sPw[(mt * 16 + lg * 4 + r) * 72 + nt * 16 + lr] = f2bf(p);
            }
#pragma unroll
            for (int m = 1; m < 16; m <<= 1) rs += __shfl_xor(rs, m, 64);
            rm[mt][r] = mn;
            rl[mt][r] = rl[mt][r] * sf + rs;
#pragma unroll
            for (int et = 0; et < 4; ++et) accO[mt][et][r] *= sf;
          }
        }
        // O += P V
        __builtin_amdgcn_s_setprio(1);
#pragma unroll
        for (int kk = 0; kk < 2; ++kk) {
          bf16x8 pa0 = *reinterpret_cast<const bf16x8*>(sPw + (0 * 16 + lr) * 72 + kk * 32 + lg * 8);
          bf16x8 pa1 = *reinterpret_cast<const bf16x8*>(sPw + (1 * 16 + lr) * 72 + kk * 32 + lg * 8);
#pragma unroll
          for (int et = 0; et < 4; ++et) {
            const int vrow = et * 16 + lr;
            const int boff = ((vrow * 64 + kk * 32 + lg * 8) * 2) ^ ((vrow & 7) << 4);
            bf16x8 vf = *reinterpret_cast<const bf16x8*>((const char*)sVc + boff);
            accO[0][et] = __builtin_amdgcn_mfma_f32_16x16x32_bf16(pa0, vf, accO[0][et], 0, 0, 0);
            accO[1][et] = __builtin_amdgcn_mfma_f32_16x16x32_bf16(pa1, vf, accO[1][et], 0, 0, 0);
          }
        }
        __builtin_amdgcn_s_setprio(0);
      }
      __syncthreads();   // drains staged loads (issued a full tile ago) + sync
      cur ^= 1;
    }
    // write O (concat heads: out[b,t, h*64+e])
#pragma unroll
    for (int mt = 0; mt < 2; ++mt)
#pragma unroll
      for (int r = 0; r < 4; ++r) {
        const int q = q_lo + mt * 16 + lg * 4 + r;
        const float inv = 1.f / rl[mt][r];
#pragma unroll
        for (int et = 0; et < 4; ++et)
          out[((size_t)(b * TCTX + q)) * DM + h * HDIM + et * 16 + lr] =
              f2bf(accO[mt][et][r] * inv);
      }
  }
#undef STAGE
}

extern "C" void kernel_launch(void* const* d_in, const int* in_sizes, int n_in,
                              void* d_out, int out_size, void* d_ws, size_t ws_size,
                              hipStream_t stream)
{
  const float* x     = (const float*)d_in[0];
  const float* ln1w  = (const float*)d_in[1];
  const float* ln1b  = (const float*)d_in[2];
  const float* wq    = (const float*)d_in[3];
  const float* wk    = (const float*)d_in[4];
  const float* wvp   = (const float*)d_in[5];
  const float* wproj = (const float*)d_in[6];
  const float* bproj = (const float*)d_in[7];
  const float* ln2w  = (const float*)d_in[8];
  const float* ln2b  = (const float*)d_in[9];
  const float* w1    = (const float*)d_in[10];
  const float* b1    = (const float*)d_in[11];
  const float* w2    = (const float*)d_in[12];
  const float* b2    = (const float*)d_in[13];

  char* ws = (char*)d_ws;
  // 120 MiB layout
  unsigned short* xn     = (unsigned short*)(ws + 0);             // 16 MiB R0
  unsigned short* qkvb   = (unsigned short*)(ws + 16777216);      // 48 MiB R1
  unsigned short* vtb    = (unsigned short*)(ws + 67108864);      // 16 MiB R2
  unsigned short* ybf    = (unsigned short*)(ws + 83886080);      // 16 MiB R3
  unsigned short* wqkvT  = (unsigned short*)(ws + 100663296);     // 6 MiB
  unsigned short* wprojT = (unsigned short*)(ws + 106954752);     // 2 MiB
  unsigned short* w1T    = (unsigned short*)(ws + 109051904);     // 8 MiB
  unsigned short* w2T    = (unsigned short*)(ws + 117440512);     // 8 MiB  (ends 120 MiB)
  unsigned short* attnb  = xn;     // R0 reuse
  unsigned short* xn2    = xn;     // R0 reuse (attnb dead after proj gemm)
  unsigned short* hb     = qkvb;   // R1+R2 reuse [8192,4096]

  dim3 tb(32, 8);
  tr_f32_bf16<<<dim3(2, 32, 16), tb, 0, stream>>>(wq,  wqkvT,               1024, 64, 65536, 65536);
  tr_f32_bf16<<<dim3(2, 32, 16), tb, 0, stream>>>(wk,  wqkvT + 1024 * 1024, 1024, 64, 65536, 65536);
  tr_f32_bf16<<<dim3(2, 32, 16), tb, 0, stream>>>(wvp, wqkvT + 2048 * 1024, 1024, 64, 65536, 65536);
  tr_f32_bf16<<<dim3(32, 32, 1),  tb, 0, stream>>>(wproj, wprojT, 1024, 1024, 0, 0);
  tr_f32_bf16<<<dim3(128, 32, 1), tb, 0, stream>>>(w1, w1T, 1024, 4096, 0, 0);
  tr_f32_bf16<<<dim3(32, 128, 1), tb, 0, stream>>>(w2, w2T, 4096, 1024, 0, 0);

  ln_k<<<2048, 256, 0, stream>>>(x, ln1w, ln1b, xn);
  gemm_k<0><<<dim3(64, 24), 256, 0, stream>>>(xn, wqkvT, qkvb, nullptr, nullptr, 8192, 3072, 1024);
  tr_v<<<dim3(2, 64, 64), tb, 0, stream>>>(qkvb, vtb);
  attn_k<<<dim3(8, 64), 256, 0, stream>>>(qkvb, vtb, attnb);
  gemm_k<3><<<dim3(64, 8), 256, 0, stream>>>(attnb, wprojT, ybf, bproj, x, 8192, 1024, 1024);
  ln_bf_k<<<2048, 256, 0, stream>>>(ybf, ln2w, ln2b, xn2);
  gemm_k<2><<<dim3(64, 32), 256, 0, stream>>>(xn2, w1T, hb, b1, nullptr, 8192, 4096, 1024);
  gemm_k<4><<<dim3(64, 8), 256, 0, stream>>>(hb, w2T, d_out, b2, ybf, 8192, 1024, 4096);
}